// Round 14
// baseline (128.884 us; speedup 1.0000x reference)
//
#include <hip/hip_runtime.h>
#include <hip/hip_fp16.h>

#define D 32          // MOTIF_DIM
#define H 64          // HIDDEN

typedef __attribute__((ext_vector_type(8))) _Float16 f16x8;
typedef __attribute__((ext_vector_type(4))) float f32x4;

union AB { uint4 u; f16x8 v; __half2 h2[4]; };

// DPP 16-lane row reduction (rows of 16 = our q-groups). All VALU, no DS.
template <int CTRL>
__device__ __forceinline__ float dppadd(float x) {
  int s = __builtin_amdgcn_update_dpp(0, __float_as_int(x), CTRL, 0xF, 0xF, true);
  return x + __int_as_float(s);
}
__device__ __forceinline__ float row16_sum(float x) {
  x = dppadd<0xB1>(x);    // quad_perm [1,0,3,2]  : lane ^ 1
  x = dppadd<0x4E>(x);    // quad_perm [2,3,0,1]  : lane ^ 2
  x = dppadd<0x141>(x);   // row_half_mirror
  x = dppadd<0x140>(x);   // row_mirror
  return x;
}

// ---------------------------------------------------------------------------
// Fused prep: blocks [0, nPack) convert x fp32 -> fp16 rows (RNE);
// remaining blocks build the W1 B-fragment table in fp16 (16 frags x 64
// lanes x 8 = 16 KB). Frag f = t*4+s: lane l elem j = W1[s*32+(l>>4)*8+j][t*16+(l&15)].
// ---------------------------------------------------------------------------
__global__ __launch_bounds__(256) void prep(
    const float* __restrict__ x, const float* __restrict__ W1,
    unsigned short* __restrict__ xh, unsigned short* __restrict__ btab,
    int n4, int nPack) {
  int b = blockIdx.x;
  if (b < nPack) {
    int i = b * 256 + threadIdx.x;
    if (i < n4) {
      float4 v = ((const float4*)x)[i];
      ushort4 o;
      o.x = __half_as_ushort(__float2half(v.x));
      o.y = __half_as_ushort(__float2half(v.y));
      o.z = __half_as_ushort(__float2half(v.z));
      o.w = __half_as_ushort(__float2half(v.w));
      ((ushort4*)xh)[i] = o;
    }
  } else {
    int id = (b - nPack) * 256 + threadIdx.x;      // 0..8191
    if (id < 16 * 64 * 8) {
      int j = id & 7;
      int l = (id >> 3) & 63;
      int f = id >> 9;
      int s = f & 3, t = f >> 2;
      int k = s * 32 + (l >> 4) * 8 + j;
      int n = t * 16 + (l & 15);
      btab[id] = __half_as_ushort(__float2half(W1[k * H + n]));
    }
  }
}

// ---------------------------------------------------------------------------
// Main: GROUPS of 4 consecutive 16-edge tiles (64 edges) per wave iteration,
// grid-stride. Per group: 2 coalesced idx loads (src/dst, one dword per lane)
// + 8 shfl distributes; 8 gathered uint4 per lane; B-fragment reuse x4 (each
// of the 16 B-frags ds_read ONCE per group, feeds 4 tiles' MFMAs); fused
// layer-2 + DPP reduce + sigmoid. Cross-group prefetch of idx and gathers.
// Anti-LICM opacifier on the INTEGER LDS offset only (pointer opacification
// kills LDS provenance -> flat_load, the R10/R11 bug).
// ---------------------------------------------------------------------------
__global__ __launch_bounds__(256) void edge_mfma(
    const unsigned short* __restrict__ xh, const unsigned short* __restrict__ btab,
    const int* __restrict__ ei,
    const float* __restrict__ b1, const float* __restrict__ W2,
    const float* __restrict__ b2, float* __restrict__ out,
    int nE, int nGroups) {
  __shared__ _Float16 lds_b[16 * 64 * 8];   // 16 KB

  // stage B table: 1024 uint4, 256 threads x 4 (coalesced)
  {
    const uint4* src = (const uint4*)btab;
    uint4* dst = (uint4*)lds_b;
#pragma unroll
    for (int i = 0; i < 4; ++i)
      dst[threadIdx.x + i * 256] = src[threadIdx.x + i * 256];
  }
  __syncthreads();

  int lane = threadIdx.x & 63;
  int wid  = (blockIdx.x * 256 + threadIdx.x) >> 6;
  int nW   = (gridDim.x * 256) >> 6;
  int m = lane & 15;        // edge-in-tile (A rows) / hidden-in-tile (C cols)
  int q = lane >> 4;        // quad
  if (wid >= nGroups) return;

  float b1v[4], w2v[4];
#pragma unroll
  for (int t = 0; t < 4; ++t) {
    b1v[t] = b1[t * 16 + m];
    w2v[t] = W2[t * 16 + m];
  }
  float bias2 = b2[0];

  const uint4* xb = (const uint4*)xh;    // node row = 4 uint4; lane reads row*4+q
  int eLim = nE - 1;
  int gLim = nGroups - 1;

  // ---- prologue: idx(g) -> gathers(g); idx(g+nW) in flight ----
  int g = wid;
  int idxS, idxD;
  uint4 amu[4], amv[4];
  {
    int e0 = g * 64 + lane; e0 = e0 < nE ? e0 : eLim;
    idxS = ei[e0]; idxD = ei[e0 + nE];
#pragma unroll
    for (int t = 0; t < 4; ++t) {
      int sn = __shfl(idxS, t * 16 + m);
      int dn = __shfl(idxD, t * 16 + m);
      amu[t] = xb[sn * 4 + q];
      amv[t] = xb[dn * 4 + q];
    }
    int g1 = g + nW; g1 = g1 < nGroups ? g1 : gLim;
    int e1 = g1 * 64 + lane; e1 = e1 < nE ? e1 : eLim;
    idxS = ei[e1]; idxD = ei[e1 + nE];
  }

#pragma unroll 2
  for (; g < nGroups; ) {
    int gn = g + nW;
    // distribute next group's ids, issue its gathers
    uint4 bmu[4], bmv[4];
#pragma unroll
    for (int t = 0; t < 4; ++t) {
      int sn = __shfl(idxS, t * 16 + m);
      int dn = __shfl(idxD, t * 16 + m);
      bmu[t] = xb[sn * 4 + q];
      bmv[t] = xb[dn * 4 + q];
    }
    // issue idx loads for g + 2nW (consumed next iteration)
    {
      int g2 = gn + nW; g2 = g2 < nGroups ? g2 : gLim;
      int e2 = g2 * 64 + lane; e2 = e2 < nE ? e2 : eLim;
      idxS = ei[e2]; idxD = ei[e2 + nE];
    }

    // c = |mu-mv|, p = mu*mv for all 4 tiles (packed fp16 VALU)
    AB mu[4], mv[4], ac[4], ap[4];
#pragma unroll
    for (int ti = 0; ti < 4; ++ti) {
      mu[ti].u = amu[ti]; mv[ti].u = amv[ti];
#pragma unroll
      for (int k = 0; k < 4; ++k) {
        ac[ti].h2[k] = __habs2(__hsub2(mu[ti].h2[k], mv[ti].h2[k]));
        ap[ti].h2[k] = __hmul2(mu[ti].h2[k], mv[ti].h2[k]);
      }
    }

    // opaque INTEGER offset (keeps lds_b provenance -> ds_read_b128)
    int bofs = lane * 8;
    asm volatile("" : "+v"(bofs));
    const _Float16* bl = lds_b + bofs;

    float part[4][4];
#pragma unroll
    for (int t = 0; t < 4; ++t) {
      float bv = b1v[t];
      f32x4 acc0 = (f32x4){bv, bv, bv, bv};
      f32x4 acc1 = (f32x4){bv, bv, bv, bv};
      f32x4 acc2 = (f32x4){bv, bv, bv, bv};
      f32x4 acc3 = (f32x4){bv, bv, bv, bv};
      // one ds_read per fragment, four MFMAs (all tiles)
      f16x8 B0 = *(const f16x8*)(bl + (t * 4 + 0) * 512);
      acc0 = __builtin_amdgcn_mfma_f32_16x16x32_f16(mu[0].v, B0, acc0, 0, 0, 0);
      acc1 = __builtin_amdgcn_mfma_f32_16x16x32_f16(mu[1].v, B0, acc1, 0, 0, 0);
      acc2 = __builtin_amdgcn_mfma_f32_16x16x32_f16(mu[2].v, B0, acc2, 0, 0, 0);
      acc3 = __builtin_amdgcn_mfma_f32_16x16x32_f16(mu[3].v, B0, acc3, 0, 0, 0);
      f16x8 B1 = *(const f16x8*)(bl + (t * 4 + 1) * 512);
      acc0 = __builtin_amdgcn_mfma_f32_16x16x32_f16(mv[0].v, B1, acc0, 0, 0, 0);
      acc1 = __builtin_amdgcn_mfma_f32_16x16x32_f16(mv[1].v, B1, acc1, 0, 0, 0);
      acc2 = __builtin_amdgcn_mfma_f32_16x16x32_f16(mv[2].v, B1, acc2, 0, 0, 0);
      acc3 = __builtin_amdgcn_mfma_f32_16x16x32_f16(mv[3].v, B1, acc3, 0, 0, 0);
      f16x8 B2 = *(const f16x8*)(bl + (t * 4 + 2) * 512);
      acc0 = __builtin_amdgcn_mfma_f32_16x16x32_f16(ac[0].v, B2, acc0, 0, 0, 0);
      acc1 = __builtin_amdgcn_mfma_f32_16x16x32_f16(ac[1].v, B2, acc1, 0, 0, 0);
      acc2 = __builtin_amdgcn_mfma_f32_16x16x32_f16(ac[2].v, B2, acc2, 0, 0, 0);
      acc3 = __builtin_amdgcn_mfma_f32_16x16x32_f16(ac[3].v, B2, acc3, 0, 0, 0);
      f16x8 B3 = *(const f16x8*)(bl + (t * 4 + 3) * 512);
      acc0 = __builtin_amdgcn_mfma_f32_16x16x32_f16(ap[0].v, B3, acc0, 0, 0, 0);
      acc1 = __builtin_amdgcn_mfma_f32_16x16x32_f16(ap[1].v, B3, acc1, 0, 0, 0);
      acc2 = __builtin_amdgcn_mfma_f32_16x16x32_f16(ap[2].v, B3, acc2, 0, 0, 0);
      acc3 = __builtin_amdgcn_mfma_f32_16x16x32_f16(ap[3].v, B3, acc3, 0, 0, 0);
#pragma unroll
      for (int r = 0; r < 4; ++r) {
        float h0 = fmaxf(acc0[r], 0.f);
        float h1 = fmaxf(acc1[r], 0.f);
        float h2 = fmaxf(acc2[r], 0.f);
        float h3 = fmaxf(acc3[r], 0.f);
        if (t == 0) {
          part[0][r] = h0 * w2v[0]; part[1][r] = h1 * w2v[0];
          part[2][r] = h2 * w2v[0]; part[3][r] = h3 * w2v[0];
        } else {
          part[0][r] = fmaf(h0, w2v[t], part[0][r]);
          part[1][r] = fmaf(h1, w2v[t], part[1][r]);
          part[2][r] = fmaf(h2, w2v[t], part[2][r]);
          part[3][r] = fmaf(h3, w2v[t], part[3][r]);
        }
      }
    }

#pragma unroll
    for (int ti = 0; ti < 4; ++ti)
#pragma unroll
      for (int r = 0; r < 4; ++r)
        part[ti][r] = row16_sum(part[ti][r]);

    if (m < 4) {
#pragma unroll
      for (int ti = 0; ti < 4; ++ti) {
        int ew = g * 64 + ti * 16 + q * 4 + m;
        if (ew < nE) {
          float z = (m == 0 ? part[ti][0] : m == 1 ? part[ti][1]
                     : m == 2 ? part[ti][2] : part[ti][3]) + bias2;
          out[ew] = 1.f / (1.f + __expf(-z));   // sigmoid in (0,1)
        }
      }
    }

#pragma unroll
    for (int t = 0; t < 4; ++t) { amu[t] = bmu[t]; amv[t] = bmv[t]; }
    g = gn;
  }
}

// ---------------------------------------------------------------------------
// Fallback (ws too small): all-fp32 per edge, no workspace needed.
// ---------------------------------------------------------------------------
__global__ __launch_bounds__(256) void edge_full(
    const float* __restrict__ x, const int* __restrict__ ei,
    const float* __restrict__ W1, const float* __restrict__ b1,
    const float* __restrict__ W2, const float* __restrict__ b2,
    float* __restrict__ out, int nE) {
  int e = blockIdx.x * 256 + threadIdx.x;
  if (e >= nE) return;
  int s = ei[e];
  int d = ei[e + nE];
  const float4* mu4 = (const float4*)(x + (size_t)s * D);
  const float4* mv4 = (const float4*)(x + (size_t)d * D);
  float mu[D], mv[D], c[D], p[D];
#pragma unroll
  for (int qq = 0; qq < D / 4; ++qq) {
    float4 a = mu4[qq];
    float4 b = mv4[qq];
    mu[4*qq+0] = a.x; mv[4*qq+0] = b.x; c[4*qq+0] = fabsf(a.x-b.x); p[4*qq+0] = a.x*b.x;
    mu[4*qq+1] = a.y; mv[4*qq+1] = b.y; c[4*qq+1] = fabsf(a.y-b.y); p[4*qq+1] = a.y*b.y;
    mu[4*qq+2] = a.z; mv[4*qq+2] = b.z; c[4*qq+2] = fabsf(a.z-b.z); p[4*qq+2] = a.z*b.z;
    mu[4*qq+3] = a.w; mv[4*qq+3] = b.w; c[4*qq+3] = fabsf(a.w-b.w); p[4*qq+3] = a.w*b.w;
  }
  float z = b2[0];
  for (int j = 0; j < H; ++j) {
    float a = b1[j];
#pragma unroll
    for (int k = 0; k < D; ++k) {
      a = fmaf(mu[k], W1[k * H + j], a);
      a = fmaf(mv[k], W1[(D + k) * H + j], a);
      a = fmaf(c[k],  W1[(2 * D + k) * H + j], a);
      a = fmaf(p[k],  W1[(3 * D + k) * H + j], a);
    }
    a = fmaxf(a, 0.f);
    z = fmaf(a, W2[j], z);
  }
  float g = 1.f / (1.f + __expf(-z));
  out[e] = fminf(fmaxf(g, 0.f), 1.f);
}

extern "C" void kernel_launch(void* const* d_in, const int* in_sizes, int n_in,
                              void* d_out, int out_size, void* d_ws, size_t ws_size,
                              hipStream_t stream) {
  const float* x  = (const float*)d_in[0];
  const int*   ei = (const int*)d_in[1];
  const float* W1 = (const float*)d_in[2];
  const float* b1 = (const float*)d_in[3];
  const float* W2 = (const float*)d_in[4];
  const float* b2 = (const float*)d_in[5];
  float* out = (float*)d_out;

  int nN = in_sizes[0] / D;      // 100000
  int nE = in_sizes[1] / 2;      // 1600000

  size_t xh_shorts = (size_t)nN * D;                      // 6.4 MB
  size_t need = (xh_shorts + 16 * 64 * 8) * sizeof(unsigned short);
  if (ws_size >= need) {
    unsigned short* xh   = (unsigned short*)d_ws;
    unsigned short* btab = xh + xh_shorts;
    int n4 = nN * D / 4;
    int nPack = (n4 + 255) / 256;
    int nBt = (16 * 64 * 8 + 255) / 256;
    prep<<<nPack + nBt, 256, 0, stream>>>(x, W1, xh, btab, n4, nPack);
    int nGroups = (nE + 63) / 64;
    edge_mfma<<<2048, 256, 0, stream>>>(xh, btab, ei, b1, W2, b2, out, nE, nGroups);
  } else {
    edge_full<<<(nE + 255) / 256, 256, 0, stream>>>(x, ei, W1, b1, W2, b2, out, nE);
  }
}

// Round 15
// 116.057 us; speedup vs baseline: 1.1105x; 1.1105x over previous
//
#include <hip/hip_runtime.h>
#include <hip/hip_fp16.h>

#define D 32          // MOTIF_DIM
#define H 64          // HIDDEN

typedef __attribute__((ext_vector_type(8))) _Float16 f16x8;
typedef __attribute__((ext_vector_type(4))) float f32x4;

union AB { uint4 u; f16x8 v; __half2 h2[4]; };

// DPP 16-lane row reduction (rows of 16 = our q-groups). All VALU, no DS.
template <int CTRL>
__device__ __forceinline__ float dppadd(float x) {
  int s = __builtin_amdgcn_update_dpp(0, __float_as_int(x), CTRL, 0xF, 0xF, true);
  return x + __int_as_float(s);
}
__device__ __forceinline__ float row16_sum(float x) {
  x = dppadd<0xB1>(x);    // quad_perm [1,0,3,2]  : lane ^ 1
  x = dppadd<0x4E>(x);    // quad_perm [2,3,0,1]  : lane ^ 2
  x = dppadd<0x141>(x);   // row_half_mirror
  x = dppadd<0x140>(x);   // row_mirror
  return x;
}

// ---------------------------------------------------------------------------
// Fused prep: blocks [0, nPack) convert x fp32 -> fp16 rows (RNE);
// remaining blocks build the W1 B-fragment table in fp16 (16 frags x 64
// lanes x 8 = 16 KB). Frag f = t*4+s: lane l elem j = W1[s*32+(l>>4)*8+j][t*16+(l&15)].
// ---------------------------------------------------------------------------
__global__ __launch_bounds__(256) void prep(
    const float* __restrict__ x, const float* __restrict__ W1,
    unsigned short* __restrict__ xh, unsigned short* __restrict__ btab,
    int n4, int nPack) {
  int b = blockIdx.x;
  if (b < nPack) {
    int i = b * 256 + threadIdx.x;
    if (i < n4) {
      float4 v = ((const float4*)x)[i];
      ushort4 o;
      o.x = __half_as_ushort(__float2half(v.x));
      o.y = __half_as_ushort(__float2half(v.y));
      o.z = __half_as_ushort(__float2half(v.z));
      o.w = __half_as_ushort(__float2half(v.w));
      ((ushort4*)xh)[i] = o;
    }
  } else {
    int id = (b - nPack) * 256 + threadIdx.x;      // 0..8191
    if (id < 16 * 64 * 8) {
      int j = id & 7;
      int l = (id >> 3) & 63;
      int f = id >> 9;
      int s = f & 3, t = f >> 2;
      int k = s * 32 + (l >> 4) * 8 + j;
      int n = t * 16 + (l & 15);
      btab[id] = __half_as_ushort(__float2half(W1[k * H + n]));
    }
  }
}

// ---------------------------------------------------------------------------
// Compute a PAIR of 16-edge tiles with B-fragment reuse: each of the 16
// B-frags is ds_read ONCE per pair and feeds both tiles' MFMAs. A-frags:
// mu,mv gathered fp16; c,p via packed-fp16 VALU. Bias as MFMA C-input;
// fused layer-2, DPP row-reduce, sigmoid, guarded writes.
// ---------------------------------------------------------------------------
__device__ __forceinline__ void compute_pair(
    uint4 mu0U, uint4 mv0U, uint4 mu1U, uint4 mv1U,
    const _Float16* __restrict__ bl,
    const float* __restrict__ b1v, const float* __restrict__ w2v, float bias2,
    int pair, int q, int m, int nE, float* __restrict__ out) {
  AB mu0, mv0, mu1, mv1, ac0, ap0, ac1, ap1;
  mu0.u = mu0U; mv0.u = mv0U; mu1.u = mu1U; mv1.u = mv1U;
#pragma unroll
  for (int k = 0; k < 4; ++k) {
    ac0.h2[k] = __habs2(__hsub2(mu0.h2[k], mv0.h2[k]));
    ap0.h2[k] = __hmul2(mu0.h2[k], mv0.h2[k]);
    ac1.h2[k] = __habs2(__hsub2(mu1.h2[k], mv1.h2[k]));
    ap1.h2[k] = __hmul2(mu1.h2[k], mv1.h2[k]);
  }

  float part0[4], part1[4];
#pragma unroll
  for (int t = 0; t < 4; ++t) {
    float bv = b1v[t];
    f32x4 acc0 = (f32x4){bv, bv, bv, bv};
    f32x4 acc1 = (f32x4){bv, bv, bv, bv};
    // one ds_read per fragment, two MFMAs (both tiles)
    f16x8 B0 = *(const f16x8*)(bl + (t * 4 + 0) * 512);
    acc0 = __builtin_amdgcn_mfma_f32_16x16x32_f16(mu0.v, B0, acc0, 0, 0, 0);
    acc1 = __builtin_amdgcn_mfma_f32_16x16x32_f16(mu1.v, B0, acc1, 0, 0, 0);
    f16x8 B1 = *(const f16x8*)(bl + (t * 4 + 1) * 512);
    acc0 = __builtin_amdgcn_mfma_f32_16x16x32_f16(mv0.v, B1, acc0, 0, 0, 0);
    acc1 = __builtin_amdgcn_mfma_f32_16x16x32_f16(mv1.v, B1, acc1, 0, 0, 0);
    f16x8 B2 = *(const f16x8*)(bl + (t * 4 + 2) * 512);
    acc0 = __builtin_amdgcn_mfma_f32_16x16x32_f16(ac0.v, B2, acc0, 0, 0, 0);
    acc1 = __builtin_amdgcn_mfma_f32_16x16x32_f16(ac1.v, B2, acc1, 0, 0, 0);
    f16x8 B3 = *(const f16x8*)(bl + (t * 4 + 3) * 512);
    acc0 = __builtin_amdgcn_mfma_f32_16x16x32_f16(ap0.v, B3, acc0, 0, 0, 0);
    acc1 = __builtin_amdgcn_mfma_f32_16x16x32_f16(ap1.v, B3, acc1, 0, 0, 0);
#pragma unroll
    for (int r = 0; r < 4; ++r) {
      float h0 = fmaxf(acc0[r], 0.f);
      float h1 = fmaxf(acc1[r], 0.f);
      part0[r] = (t == 0) ? h0 * w2v[0] : fmaf(h0, w2v[t], part0[r]);
      part1[r] = (t == 0) ? h1 * w2v[0] : fmaf(h1, w2v[t], part1[r]);
    }
  }

#pragma unroll
  for (int r = 0; r < 4; ++r) {
    part0[r] = row16_sum(part0[r]);
    part1[r] = row16_sum(part1[r]);
  }

  if (m < 4) {
    float z0 = (m == 0 ? part0[0] : m == 1 ? part0[1] : m == 2 ? part0[2] : part0[3]) + bias2;
    float z1 = (m == 0 ? part1[0] : m == 1 ? part1[1] : m == 2 ? part1[2] : part1[3]) + bias2;
    int ew0 = pair * 32 + q * 4 + m;
    int ew1 = pair * 32 + 16 + q * 4 + m;
    if (ew0 < nE) out[ew0] = 1.f / (1.f + __expf(-z0));
    if (ew1 < nE) out[ew1] = 1.f / (1.f + __expf(-z1));
  }
}

// ---------------------------------------------------------------------------
// Main: pairs of consecutive 16-edge tiles per wave, grid-stride; coalesced
// idx load + shfl distribute; idx/gather prefetch pipeline. B table staged
// into LDS with coalesced uint4 copies. Anti-LICM opacifier on the INTEGER
// offset only (pointer opacification kills LDS provenance -> flat_load).
// __launch_bounds__(256,4): cap unified regfile at 128/wave to force
// 4 waves/SIMD — R13's kernel needs only ~100, so no spill expected
// (R8's spill came from 64 regs of B held in-file; B now lives in LDS).
// ---------------------------------------------------------------------------
__global__ __launch_bounds__(256, 4) void edge_mfma(
    const unsigned short* __restrict__ xh, const unsigned short* __restrict__ btab,
    const int* __restrict__ ei,
    const float* __restrict__ b1, const float* __restrict__ W2,
    const float* __restrict__ b2, float* __restrict__ out,
    int nE, int nPairs) {
  __shared__ _Float16 lds_b[16 * 64 * 8];   // 16 KB

  // stage B table: 1024 uint4, 256 threads x 4 (coalesced)
  {
    const uint4* src = (const uint4*)btab;
    uint4* dst = (uint4*)lds_b;
#pragma unroll
    for (int i = 0; i < 4; ++i)
      dst[threadIdx.x + i * 256] = src[threadIdx.x + i * 256];
  }
  __syncthreads();

  int lane = threadIdx.x & 63;
  int wid  = (blockIdx.x * 256 + threadIdx.x) >> 6;
  int nW   = (gridDim.x * 256) >> 6;
  int m = lane & 15;        // edge-in-tile (A rows) / hidden-in-tile (C cols)
  int q = lane >> 4;        // quad
  if (wid >= nPairs) return;

  float b1v[4], w2v[4];
#pragma unroll
  for (int t = 0; t < 4; ++t) {
    b1v[t] = b1[t * 16 + m];
    w2v[t] = W2[t * 16 + m];
  }
  float bias2 = b2[0];

  const uint4* xb = (const uint4*)xh;    // node row = 4 uint4; lane reads row*4+q
  int eLim = nE - 1;
  int pLim = nPairs - 1;
  int selOff = (lane >> 5) ? nE : 0;     // src half / dst half
  int eoff = lane & 31;

  // ---- prologue ----
  int p = wid;
  int idxNxt;
  uint4 amu0, amv0, amu1, amv1;
  {
    int e = p * 32 + eoff; e = e < nE ? e : eLim;
    int idxCur = ei[selOff + e];
    int sn0 = __shfl(idxCur, m);
    int sn1 = __shfl(idxCur, 16 + m);
    int dn0 = __shfl(idxCur, 32 + m);
    int dn1 = __shfl(idxCur, 48 + m);
    amu0 = xb[sn0 * 4 + q]; amv0 = xb[dn0 * 4 + q];
    amu1 = xb[sn1 * 4 + q]; amv1 = xb[dn1 * 4 + q];
    int p1 = p + nW; p1 = p1 < nPairs ? p1 : pLim;
    int e1 = p1 * 32 + eoff; e1 = e1 < nE ? e1 : eLim;
    idxNxt = ei[selOff + e1];
  }

  while (p < nPairs) {
    int pn = p + nW;
    // distribute next pair's ids, issue its gathers
    int sn0 = __shfl(idxNxt, m);
    int sn1 = __shfl(idxNxt, 16 + m);
    int dn0 = __shfl(idxNxt, 32 + m);
    int dn1 = __shfl(idxNxt, 48 + m);
    uint4 bmu0 = xb[sn0 * 4 + q], bmv0 = xb[dn0 * 4 + q];
    uint4 bmu1 = xb[sn1 * 4 + q], bmv1 = xb[dn1 * 4 + q];
    // issue idx load for p + 2nW (consumed next iteration)
    {
      int p2 = pn + nW; p2 = p2 < nPairs ? p2 : pLim;
      int e2 = p2 * 32 + eoff; e2 = e2 < nE ? e2 : eLim;
      idxNxt = ei[selOff + e2];
    }

    // opaque INTEGER offset (keeps lds_b provenance -> ds_read_b128)
    int bofs = lane * 8;
    asm volatile("" : "+v"(bofs));
    const _Float16* bl = lds_b + bofs;

    compute_pair(amu0, amv0, amu1, amv1, bl, b1v, w2v, bias2, p, q, m, nE, out);

    amu0 = bmu0; amv0 = bmv0; amu1 = bmu1; amv1 = bmv1;
    p = pn;
  }
}

// ---------------------------------------------------------------------------
// Fallback (ws too small): all-fp32 per edge, no workspace needed.
// ---------------------------------------------------------------------------
__global__ __launch_bounds__(256) void edge_full(
    const float* __restrict__ x, const int* __restrict__ ei,
    const float* __restrict__ W1, const float* __restrict__ b1,
    const float* __restrict__ W2, const float* __restrict__ b2,
    float* __restrict__ out, int nE) {
  int e = blockIdx.x * 256 + threadIdx.x;
  if (e >= nE) return;
  int s = ei[e];
  int d = ei[e + nE];
  const float4* mu4 = (const float4*)(x + (size_t)s * D);
  const float4* mv4 = (const float4*)(x + (size_t)d * D);
  float mu[D], mv[D], c[D], p[D];
#pragma unroll
  for (int qq = 0; qq < D / 4; ++qq) {
    float4 a = mu4[qq];
    float4 b = mv4[qq];
    mu[4*qq+0] = a.x; mv[4*qq+0] = b.x; c[4*qq+0] = fabsf(a.x-b.x); p[4*qq+0] = a.x*b.x;
    mu[4*qq+1] = a.y; mv[4*qq+1] = b.y; c[4*qq+1] = fabsf(a.y-b.y); p[4*qq+1] = a.y*b.y;
    mu[4*qq+2] = a.z; mv[4*qq+2] = b.z; c[4*qq+2] = fabsf(a.z-b.z); p[4*qq+2] = a.z*b.z;
    mu[4*qq+3] = a.w; mv[4*qq+3] = b.w; c[4*qq+3] = fabsf(a.w-b.w); p[4*qq+3] = a.w*b.w;
  }
  float z = b2[0];
  for (int j = 0; j < H; ++j) {
    float a = b1[j];
#pragma unroll
    for (int k = 0; k < D; ++k) {
      a = fmaf(mu[k], W1[k * H + j], a);
      a = fmaf(mv[k], W1[(D + k) * H + j], a);
      a = fmaf(c[k],  W1[(2 * D + k) * H + j], a);
      a = fmaf(p[k],  W1[(3 * D + k) * H + j], a);
    }
    a = fmaxf(a, 0.f);
    z = fmaf(a, W2[j], z);
  }
  float g = 1.f / (1.f + __expf(-z));
  out[e] = fminf(fmaxf(g, 0.f), 1.f);
}

extern "C" void kernel_launch(void* const* d_in, const int* in_sizes, int n_in,
                              void* d_out, int out_size, void* d_ws, size_t ws_size,
                              hipStream_t stream) {
  const float* x  = (const float*)d_in[0];
  const int*   ei = (const int*)d_in[1];
  const float* W1 = (const float*)d_in[2];
  const float* b1 = (const float*)d_in[3];
  const float* W2 = (const float*)d_in[4];
  const float* b2 = (const float*)d_in[5];
  float* out = (float*)d_out;

  int nN = in_sizes[0] / D;      // 100000
  int nE = in_sizes[1] / 2;      // 1600000

  size_t xh_shorts = (size_t)nN * D;                      // 6.4 MB
  size_t need = (xh_shorts + 16 * 64 * 8) * sizeof(unsigned short);
  if (ws_size >= need) {
    unsigned short* xh   = (unsigned short*)d_ws;
    unsigned short* btab = xh + xh_shorts;
    int n4 = nN * D / 4;
    int nPack = (n4 + 255) / 256;
    int nBt = (16 * 64 * 8 + 255) / 256;
    prep<<<nPack + nBt, 256, 0, stream>>>(x, W1, xh, btab, n4, nPack);
    int nTiles = (nE + 15) / 16;
    int nPairs = (nTiles + 1) / 2;
    edge_mfma<<<2048, 256, 0, stream>>>(xh, btab, ei, b1, W2, b2, out, nE, nPairs);
  } else {
    edge_full<<<(nE + 255) / 256, 256, 0, stream>>>(x, ei, W1, b1, W2, b2, out, nE);
  }
}